// Round 2
// baseline (309.242 us; speedup 1.0000x reference)
//
#include <hip/hip_runtime.h>

// MRR on MI355X. N_TOT = 8192 + 8192*4000 = 32,776,192 (divisible by 4).
// argsort(index) of a permutation is its inverse: element j is pos slot
// index[j] if index[j] < 8192, else a neg of row (index[j]-8192)/4000.
//
// Pass 1 (scatter): stream index, write 8192 pos values.        ~131 MB read
// Pass 2 (count):   stream index+pv, LDS pos stage, LDS u32     ~262 MB read
//                   counters, flush per-block packed u64 slab     +8 MB write
//                   (NO global atomics — that was R1's suspected sink).
// Pass 3 (reduce):  sum 512 slab slices (u64 adds are safe: 16-bit fields
//                   total <= 4000, never carry), emit sample_mrr + mean.
//
// ws layout: [0,32KB) pos floats; [32KB, 32KB+8MB) u64 slab[512][2048].

constexpr int N_POS = 8192;
constexpr int N_NEG = 4000;
constexpr int CNT_BLOCKS = 512;      // 2 blocks/CU at 1024 thr, 64 KB LDS
constexpr int NSLOT = N_POS / 4;     // 2048 packed u64 slots (4 rows each)

typedef int   vint4   __attribute__((ext_vector_type(4)));
typedef float vfloat4 __attribute__((ext_vector_type(4)));
typedef unsigned int  u32;
typedef unsigned long long u64;

__global__ __launch_bounds__(256) void scatter_pos_kernel(
    const vint4* __restrict__ idx4, const float* __restrict__ pv,
    float* __restrict__ pos, int nvec) {
  const int stride = gridDim.x * blockDim.x;
  int j = blockIdx.x * blockDim.x + threadIdx.x;
#define SC_ELEM(V, JJ)                                   \
  if ((V).x < N_POS) pos[(V).x] = pv[4 * (JJ) + 0];      \
  if ((V).y < N_POS) pos[(V).y] = pv[4 * (JJ) + 1];      \
  if ((V).z < N_POS) pos[(V).z] = pv[4 * (JJ) + 2];      \
  if ((V).w < N_POS) pos[(V).w] = pv[4 * (JJ) + 3];
  for (; j + stride < nvec; j += 2 * stride) {
    vint4 a = __builtin_nontemporal_load(&idx4[j]);
    vint4 b = __builtin_nontemporal_load(&idx4[j + stride]);
    SC_ELEM(a, j)
    SC_ELEM(b, j + stride)
  }
  for (; j < nvec; j += stride) {
    vint4 a = __builtin_nontemporal_load(&idx4[j]);
    SC_ELEM(a, j)
  }
#undef SC_ELEM
}

__global__ __launch_bounds__(1024) void count_kernel(
    const vint4* __restrict__ idx4, const vfloat4* __restrict__ pv4,
    const float* __restrict__ pos, u64* __restrict__ slab, int nvec) {
  __shared__ float pos_lds[N_POS];   // 32 KB
  __shared__ u32 lcnt[N_POS];        // 32 KB, unpacked u32 counters
  for (int i = threadIdx.x; i < N_POS; i += 1024) {
    pos_lds[i] = pos[i];
    lcnt[i] = 0u;
  }
  __syncthreads();

  const int stride = gridDim.x * blockDim.x;
  int j = blockIdx.x * blockDim.x + threadIdx.x;
#define CT_ELEM(IV, XV)                                              \
  if ((IV) >= N_POS) {                                               \
    unsigned r = (unsigned)((IV) - N_POS) / (unsigned)N_NEG;         \
    if ((XV) > pos_lds[r]) atomicAdd(&lcnt[r], 1u);                  \
  }
#define CT_VEC(V, X)                                                 \
  CT_ELEM((V).x, (X).x) CT_ELEM((V).y, (X).y)                        \
  CT_ELEM((V).z, (X).z) CT_ELEM((V).w, (X).w)
  for (; j + stride < nvec; j += 2 * stride) {
    vint4 va = __builtin_nontemporal_load(&idx4[j]);
    vint4 vb = __builtin_nontemporal_load(&idx4[j + stride]);
    vfloat4 xa = __builtin_nontemporal_load(&pv4[j]);
    vfloat4 xb = __builtin_nontemporal_load(&pv4[j + stride]);
    CT_VEC(va, xa)
    CT_VEC(vb, xb)
  }
  for (; j < nvec; j += stride) {
    vint4 va = __builtin_nontemporal_load(&idx4[j]);
    vfloat4 xa = __builtin_nontemporal_load(&pv4[j]);
    CT_VEC(va, xa)
  }
#undef CT_VEC
#undef CT_ELEM
  __syncthreads();

  // Non-atomic flush: this block's private 16 KB slab slice, coalesced.
  u64* my = slab + (size_t)blockIdx.x * NSLOT;
  const uint4* lq = (const uint4*)lcnt;  // b128 reads of 4 counters
  for (int s = threadIdx.x; s < NSLOT; s += 1024) {
    uint4 q = lq[s];
    u64 p = (u64)(q.x & 0xFFFFu) | ((u64)(q.y & 0xFFFFu) << 16) |
            ((u64)(q.z & 0xFFFFu) << 32) | ((u64)(q.w & 0xFFFFu) << 48);
    __builtin_nontemporal_store(p, &my[s]);
  }
}

// 16 blocks x 1024 threads. Thread k: slot = k>>3 (0..2047), part = k&7.
// Each part sums 64 of the 512 slab slices; 8-lane shuffle tree finishes.
__global__ __launch_bounds__(1024) void reduce_kernel(
    const u64* __restrict__ slab, float* __restrict__ out) {
  int k = blockIdx.x * 1024 + threadIdx.x;
  int slot = k >> 3, part = k & 7;
  u64 acc = 0;
  const u64* base = slab + (size_t)(part * 64) * NSLOT + slot;
#pragma unroll 8
  for (int b = 0; b < 64; ++b) acc += base[(size_t)b * NSLOT];
  acc += __shfl_down(acc, 4, 64);
  acc += __shfl_down(acc, 2, 64);
  acc += __shfl_down(acc, 1, 64);

  float lsum = 0.f;
  if (part == 0) {
    float m0 = 1.0f / (float)(1u + (u32)(acc & 0xFFFFu));
    float m1 = 1.0f / (float)(1u + (u32)((acc >> 16) & 0xFFFFu));
    float m2 = 1.0f / (float)(1u + (u32)((acc >> 32) & 0xFFFFu));
    float m3 = 1.0f / (float)(1u + (u32)((acc >> 48) & 0xFFFFu));
    vfloat4 m = {m0, m1, m2, m3};
    *(vfloat4*)&out[1 + 4 * slot] = m;
    lsum = m0 + m1 + m2 + m3;
  }
  // block reduce lsum, then one atomic per block into out[0]
  __shared__ float wsum[16];
#pragma unroll
  for (int off = 32; off > 0; off >>= 1) lsum += __shfl_down(lsum, off, 64);
  int t = threadIdx.x;
  if ((t & 63) == 0) wsum[t >> 6] = lsum;
  __syncthreads();
  if (t < 64) {
    float v = (t < 16) ? wsum[t] : 0.f;
#pragma unroll
    for (int off = 8; off > 0; off >>= 1) v += __shfl_down(v, off, 64);
    if (t == 0) atomicAdd(&out[0], v / (float)N_POS);
  }
}

extern "C" void kernel_launch(void* const* d_in, const int* in_sizes, int n_in,
                              void* d_out, int out_size, void* d_ws, size_t ws_size,
                              hipStream_t stream) {
  const float* pv = (const float*)d_in[0];
  const int* idx = (const int*)d_in[1];
  float* out = (float*)d_out;

  float* pos = (float*)d_ws;
  u64* slab = (u64*)((char*)d_ws + 32 * 1024);

  int n = in_sizes[0];   // 32,776,192
  int nvec = n / 4;

  hipMemsetAsync(out, 0, sizeof(float), stream);  // out[0] accumulator
  scatter_pos_kernel<<<2048, 256, 0, stream>>>((const vint4*)idx, pv, pos, nvec);
  count_kernel<<<CNT_BLOCKS, 1024, 0, stream>>>((const vint4*)idx,
                                                (const vfloat4*)pv, pos, slab,
                                                nvec);
  reduce_kernel<<<16, 1024, 0, stream>>>(slab, out);
}